// Round 2
// baseline (751.017 us; speedup 1.0000x reference)
//
#include <hip/hip_runtime.h>

#define DIM 4096
#define SEQ 2048
#define NH 32
#define HD 128

typedef __bf16 bf16x8 __attribute__((ext_vector_type(8)));
typedef float f32x4 __attribute__((ext_vector_type(4)));

// log2(e) / sqrt(HD): folded into Q so softmax runs in exp2 domain
#define QSCALE 0.12751649736765598f

__device__ inline ushort f2bf(float f) {
    union { float f; unsigned u; } v; v.f = f;
    unsigned r = v.u + 0x7fffu + ((v.u >> 16) & 1u);
    return (ushort)(r >> 16);
}

// ---------------- fused fp32 -> bf16 convert for x + all 4 weights ----------------
__global__ void conv_all(const float* __restrict__ x,  const float* __restrict__ wq,
                         const float* __restrict__ wk, const float* __restrict__ wv,
                         const float* __restrict__ wo,
                         ushort* __restrict__ xb,  ushort* __restrict__ wqb,
                         ushort* __restrict__ wkb, ushort* __restrict__ wvb,
                         ushort* __restrict__ wob) {
    int i = blockIdx.x * 256 + threadIdx.x;   // over (SEQ*DIM + 4*DIM*DIM)/4 float4s
    const float* src; ushort* dst; int off;
    const int n4x = (SEQ * DIM) / 4;          // 2^21
    if (i < n4x) { src = x; dst = xb; off = i; }
    else {
        int j = i - n4x;
        int w = j >> 22;                      // DIM*DIM/4 = 2^22
        off = j & ((1 << 22) - 1);
        src = (w == 0) ? wq : (w == 1) ? wk : (w == 2) ? wv : wo;
        dst = (w == 0) ? wqb : (w == 1) ? wkb : (w == 2) ? wvb : wob;
    }
    float4 v = ((const float4*)src)[off];
    ushort4 o;
    o.x = f2bf(v.x); o.y = f2bf(v.y); o.z = f2bf(v.z); o.w = f2bf(v.w);
    ((ushort4*)dst)[off] = o;
}

// ============================================================================
// 128x256 2-phase GEMM body. BM=128, BN=256, BK=64, 512 threads = 8 waves
// (2M x 4N), per-wave C = 64x64 (4x4 frags). LDS = 2x(128x64) A + 2x(256x64) B
// = 96 KiB double-buffered.
//   Per K-tile, 2 phases:
//     p1: ds_read A-half0 (4xb128) + ALL B frags (8xb128, held in regs across
//         both phases -> 16 reads/tile = floor); stage A1(t+1) [1 load];
//         barrier; 16 MFMA; barrier.
//     p2: ds_read A-half1 (4); stage A0(t+2)+B(t+2) [5 loads]; barrier;
//         16 MFMA; vmcnt(5); barrier.
//   vmcnt(5) at tile boundary = "all of tile t+1 complete, t+2's 5 in flight"
//   (loads retire in order). Never vmcnt(0) in steady state.
//   Region safety: A1(nA) last read at p2 of t-1 (one barrier behind p1 of t);
//   A0/B of cA/cB last read at p1 of t (one barrier behind p2 of t).
//   Swizzle: row r stores global 16B-chunk g at LDS pos g^(r&7); frag rows ==
//   c (mod 8) so readers use pos (gc^(c&7)) -- 2-way bank alias only (free).
// ============================================================================

#define AS1(p) (const __attribute__((address_space(1))) void*)(p)
#define AS3(p) (__attribute__((address_space(3))) void*)(p)
#define FENCE() asm volatile("" ::: "memory")
#define BARRIER() do { FENCE(); __builtin_amdgcn_s_barrier(); FENCE(); } while (0)

__device__ __forceinline__ void gemm128x256_body(
    const ushort* __restrict__ Ab,   // pre-offset to tile row 0 (row-major, stride K)
    const ushort* __restrict__ Bb,   // pre-offset to tile col 0 (row-major, stride K)
    ushort* __restrict__ sA0, ushort* __restrict__ sA1,
    ushort* __restrict__ sB0, ushort* __restrict__ sB1,
    f32x4 acc[4][4], const int K)
{
    const int tid  = threadIdx.x;
    const int wave = tid >> 6, lane = tid & 63;
    const int quad = lane >> 4, c = lane & 15;
    const int wm = wave >> 2, wn = wave & 3;

    // staging: per global_load_lds a wave covers 8 rows x 64 cols (lane>>3 =
    // row-in-group, lane&7 = LDS chunk pos; fetch global chunk (lane&7)^(lane>>3))
    const int aoff = (lane >> 3) * K + (((lane & 7) ^ (lane >> 3)) * 8);
    // A stage: inst h covers rows {0-31,64-95}+h*32; wave w owns 8 rows:
    const int ra0 = (wave >> 2) * 64 + (wave & 3) * 8;    // + h*32
    // B stage: inst q covers rows q*64..q*64+63; wave w owns rows w*8..w*8+7:
    const int rb0 = wave * 8;                              // + q*64

    // fragment read chunk positions for the two K-sub-steps
    const int rp0 = ((0 * 4 + quad) ^ (c & 7)) * 8;
    const int rp1 = ((1 * 4 + quad) ^ (c & 7)) * 8;
    const int arow = (wm * 64 + c) * 64;   // + mt*16*64
    const int brow = (wn * 64 + c) * 64;   // + nt*16*64

#define STAGE_A(dst, h, k0) do { \
    const int _r = ra0 + (h) * 32; \
    __builtin_amdgcn_global_load_lds(AS1(Ab + (size_t)_r * K + (k0) + aoff), \
                                     AS3((dst) + _r * 64), 16, 0, 0); \
  } while (0)
#define STAGE_B4(dst, k0) do { \
    _Pragma("unroll") \
    for (int _q = 0; _q < 4; ++_q) { \
        const int _r = rb0 + _q * 64; \
        __builtin_amdgcn_global_load_lds(AS1(Bb + (size_t)_r * K + (k0) + aoff), \
                                         AS3((dst) + _r * 64), 16, 0, 0); \
    } } while (0)

    bf16x8 af[2][2], bfr[4][2];

#define READ_AH(buf, h) do { \
    _Pragma("unroll") \
    for (int _i = 0; _i < 2; ++_i) { \
        af[_i][0] = *(const bf16x8*)&(buf)[arow + ((h) * 2 + _i) * 1024 + rp0]; \
        af[_i][1] = *(const bf16x8*)&(buf)[arow + ((h) * 2 + _i) * 1024 + rp1]; \
    } } while (0)
#define READ_BALL(buf) do { \
    _Pragma("unroll") \
    for (int _n = 0; _n < 4; ++_n) { \
        bfr[_n][0] = *(const bf16x8*)&(buf)[brow + _n * 1024 + rp0]; \
        bfr[_n][1] = *(const bf16x8*)&(buf)[brow + _n * 1024 + rp1]; \
    } } while (0)
#define MMA_H(h) do { \
    __builtin_amdgcn_s_setprio(1); \
    _Pragma("unroll") \
    for (int _kk = 0; _kk < 2; ++_kk) \
    _Pragma("unroll") \
    for (int _i = 0; _i < 2; ++_i) \
    _Pragma("unroll") \
    for (int _n = 0; _n < 4; ++_n) \
        acc[(h) * 2 + _i][_n] = __builtin_amdgcn_mfma_f32_16x16x32_bf16( \
            af[_i][_kk], bfr[_n][_kk], acc[(h) * 2 + _i][_n], 0, 0, 0); \
    __builtin_amdgcn_s_setprio(0); \
  } while (0)

    const int NT = K >> 6;

    // prologue: tile0 full (A0,A1,B) + tile1's A0,B; A1(t1) issued at p1 of t0
    STAGE_A(sA0, 0, 0); STAGE_A(sA0, 1, 0); STAGE_B4(sB0, 0);
    STAGE_A(sA1, 0, 64); STAGE_B4(sB1, 64);
    asm volatile("s_waitcnt vmcnt(5)" ::: "memory");
    BARRIER();

#pragma unroll 1
    for (int t = 0; t < NT; ++t) {
        ushort* cA = (t & 1) ? sA1 : sA0;
        ushort* cB = (t & 1) ? sB1 : sB0;
        ushort* nA = (t & 1) ? sA0 : sA1;
        const int kn  = (t + 1) << 6;
        const int kn2 = (t + 2) << 6;
        const bool ok1 = (t + 1 < NT), ok2 = (t + 2 < NT);

        // phase 1: A-half0 x all-B; issue A1 of tile t+1
        READ_AH(cA, 0); READ_BALL(cB);
        if (ok1) STAGE_A(nA, 1, kn);
        BARRIER();
        MMA_H(0);
        BARRIER();

        // phase 2: A-half1 x all-B (B still in regs); issue A0+B of tile t+2
        READ_AH(cA, 1);
        if (ok2) { STAGE_A(cA, 0, kn2); STAGE_B4(cB, kn2); }
        BARRIER();
        MMA_H(1);
        if (t < NT - 1) {
            if (ok2) asm volatile("s_waitcnt vmcnt(5)" ::: "memory");
            else     asm volatile("s_waitcnt vmcnt(0)" ::: "memory");
        }
        BARRIER();
    }
#undef STAGE_A
#undef STAGE_B4
#undef READ_AH
#undef READ_BALL
#undef MMA_H
}

// ---------------- fused QKV GEMM, 128x256 tiles, rotary folded into epilogue ----------------
// Grid 768 = 16 m-tiles x 48 n-tiles = 3 exact full-GPU rounds (zero tail).
// XCD n-partition: XCD x=bi&7 owns 6 n-tiles, m sweeps fastest (per-XCD B
// col-blocks stay in its L2; A 16MB stays L3-hot).
__global__ __launch_bounds__(512, 2)
void gemm_qkv(const ushort* __restrict__ A,
              const ushort* __restrict__ Bq, const ushort* __restrict__ Bk,
              const ushort* __restrict__ Bv,
              ushort* __restrict__ qout, ushort* __restrict__ kout,
              ushort* __restrict__ vt, const float* __restrict__ freqs) {
    __shared__ __align__(16) ushort sA[2][128 * 64];
    __shared__ __align__(16) ushort sB[2][256 * 64];
    const int bi = blockIdx.x;
    const int x = bi & 7;                    // XCD (round-robin dispatch)
    const int l = bi >> 3;                   // 0..95 within XCD
    const int mblk = l & 15;
    const int nblk = x * 6 + (l >> 4);       // 0..47, exclusive per XCD
    const int wsel = nblk >> 4;              // 0=q 1=k 2=v
    const int nloc = (nblk & 15) * 256;
    const int m0 = mblk * 128;
    const ushort* B = (wsel == 0) ? Bq : (wsel == 1) ? Bk : Bv;

    const f32x4 vzero = {0.f, 0.f, 0.f, 0.f};
    f32x4 acc[4][4];
#pragma unroll
    for (int i = 0; i < 4; i++)
#pragma unroll
        for (int j = 0; j < 4; j++) acc[i][j] = vzero;

    gemm128x256_body(A + (size_t)m0 * DIM, B + (size_t)nloc * DIM,
                     &sA[0][0], &sA[1][0], &sB[0][0], &sB[1][0], acc, DIM);

    const int tid = threadIdx.x;
    const int wave = tid >> 6, lane = tid & 63;
    const int quad = lane >> 4, c = lane & 15;
    const int wm = wave >> 2, wn = wave & 3;

    if (wsel < 2) {
        ushort* Cw = wsel ? kout : qout;
        const float qs = wsel ? 1.0f : QSCALE;
#pragma unroll
        for (int mt = 0; mt < 4; mt++) {
#pragma unroll
            for (int nt = 0; nt < 4; nt++) {
                int colg = nloc + wn * 64 + nt * 16 + c;
                int dh = (colg & 127) >> 1;
#pragma unroll
                for (int r = 0; r < 4; r++) {
                    int row = m0 + wm * 64 + mt * 16 + quad * 4 + r;
                    float2 f2 = ((const float2*)freqs)[row * 64 + dh];
                    float f = (f2.x + ((c & 1) ? f2.y : -f2.y)) * qs;
                    Cw[(size_t)row * DIM + colg] = f2bf(acc[mt][nt][r] * f);
                }
            }
        }
    } else {
        // V: write transposed vt[cv][seq]; lane holds 4 consecutive seq rows
#pragma unroll
        for (int mt = 0; mt < 4; mt++) {
#pragma unroll
            for (int nt = 0; nt < 4; nt++) {
                int cv = nloc + wn * 64 + nt * 16 + c;
                int row0 = m0 + wm * 64 + mt * 16 + quad * 4;
                ushort4 o;
                o.x = f2bf(acc[mt][nt][0]); o.y = f2bf(acc[mt][nt][1]);
                o.z = f2bf(acc[mt][nt][2]); o.w = f2bf(acc[mt][nt][3]);
                *(ushort4*)&vt[(size_t)cv * SEQ + row0] = o;
            }
        }
    }
}

// ---------------- bf16 GEMM, 128x256 tiles, fp32 output (final projection) ----------------
// Grid 256 = 16 m-tiles x 16 n-tiles = exactly 1 full-GPU round.
__global__ __launch_bounds__(512, 2)
void gemm_f32out(const ushort* __restrict__ A, const ushort* __restrict__ B,
                 float* __restrict__ C, int M, int N, int K) {
    __shared__ __align__(16) ushort sA[2][128 * 64];
    __shared__ __align__(16) ushort sB[2][256 * 64];
    const int bi = blockIdx.x;
    const int x = bi & 7;
    const int l = bi >> 3;                   // 0..31
    const int mblk = l & 15;
    const int nblk = x * 2 + (l >> 4);       // 0..15
    const int m0 = mblk * 128, n0 = nblk * 256;

    const f32x4 vzero = {0.f, 0.f, 0.f, 0.f};
    f32x4 acc[4][4];
#pragma unroll
    for (int i = 0; i < 4; i++)
#pragma unroll
        for (int j = 0; j < 4; j++) acc[i][j] = vzero;

    gemm128x256_body(A + (size_t)m0 * K, B + (size_t)n0 * K,
                     &sA[0][0], &sA[1][0], &sB[0][0], &sB[1][0], acc, K);

    const int tid = threadIdx.x;
    const int wave = tid >> 6, lane = tid & 63;
    const int quad = lane >> 4, c = lane & 15;
    const int wm = wave >> 2, wn = wave & 3;

#pragma unroll
    for (int mt = 0; mt < 4; mt++)
#pragma unroll
        for (int nt = 0; nt < 4; nt++)
#pragma unroll
            for (int r = 0; r < 4; r++) {
                int row = m0 + wm * 64 + mt * 16 + quad * 4 + r;
                int col = n0 + wn * 64 + nt * 16 + c;
                C[(size_t)row * N + col] = acc[mt][nt][r];
            }
}

// ---------------- flash attention (causal), balanced pairing + swizzled LDS ----------------
// 512 blocks: block handles head h = bi&31 and q-block pair {p, 31-p}, p = bi>>5
// -> exactly 33 K-tile iterations per block (perfect balance).
__global__ __launch_bounds__(256)
void flash_kernel(const ushort* __restrict__ Q, const ushort* __restrict__ K,
                  const ushort* __restrict__ Vt, ushort* __restrict__ O) {
    const int bi = blockIdx.x;
    const int h = bi & (NH - 1);
    const int p = bi >> 5;
    __shared__ __align__(16) ushort sK[64 * 128];
    __shared__ __align__(16) ushort sVt[128 * 64];
    __shared__ __align__(16) ushort sP[4][16 * 72];
    const int tid = threadIdx.x, wave = tid >> 6, lane = tid & 63;
    const int quad = lane >> 4, c = lane & 15;

    for (int pass = 0; pass < 2; pass++) {
        const int qb = pass ? (SEQ / 64 - 1 - p) : p;
        const int q0 = qb * 64;

        bf16x8 qf[4];
        {
            const ushort* Qp = Q + (size_t)(q0 + wave * 16 + c) * DIM + h * HD;
#pragma unroll
            for (int ks = 0; ks < 4; ks++) qf[ks] = *(const bf16x8*)(Qp + ks * 32 + quad * 8);
        }
        const f32x4 vzero = {0.f, 0.f, 0.f, 0.f};
        f32x4 oa[8];
#pragma unroll
        for (int dt = 0; dt < 8; dt++) oa[dt] = vzero;
        float ms[4], ls[4];
#pragma unroll
        for (int r = 0; r < 4; r++) { ms[r] = -1e30f; ls[r] = 0.f; }

        for (int kt = 0; kt <= qb; kt++) {
            __syncthreads();
            // stage K tile [64 keys][128 d]: wave covers 16 rows in 4 insts
#pragma unroll
            for (int i = 0; i < 4; i++) {
                int lr = wave * 16 + i * 4 + (lane >> 4);
                int ch = lane & 15;
                int g = (ch & 8) | ((ch ^ lr) & 7);
                __builtin_amdgcn_global_load_lds(
                    (const __attribute__((address_space(1))) void*)(K + (size_t)(kt * 64 + lr) * DIM + h * HD + g * 8),
                    (__attribute__((address_space(3))) void*)(&sK[(wave * 16 + i * 4) * 128]), 16, 0, 0);
            }
            // stage V^T tile [128 d][64 keys]: wave covers 32 rows in 4 insts
#pragma unroll
            for (int i = 0; i < 4; i++) {
                int ld = wave * 32 + i * 8 + (lane >> 3);
                int ch = lane & 7;
                int g = (ch ^ ld) & 7;
                __builtin_amdgcn_global_load_lds(
                    (const __attribute__((address_space(1))) void*)(Vt + (size_t)(h * HD + ld) * SEQ + kt * 64 + g * 8),
                    (__attribute__((address_space(3))) void*)(&sVt[(wave * 32 + i * 8) * 64]), 16, 0, 0);
            }
            __syncthreads();

            // S = Q K^T (Q pre-scaled by log2e/sqrt(HD))
            f32x4 s[4];
#pragma unroll
            for (int nt = 0; nt < 4; nt++) s[nt] = vzero;
#pragma unroll
            for (int ks = 0; ks < 4; ks++)
#pragma unroll
                for (int nt = 0; nt < 4; nt++) {
                    int lr = nt * 16 + c;
                    int gc = ks * 4 + quad;
                    int pch = (gc & 8) | ((gc ^ lr) & 7);
                    bf16x8 kf = *(const bf16x8*)&sK[lr * 128 + pch * 8];
                    s[nt] = __builtin_amdgcn_mfma_f32_16x16x32_bf16(qf[ks], kf, s[nt], 0, 0, 0);
                }

            if (kt == qb) {  // causal mask on the diagonal tile
#pragma unroll
                for (int nt = 0; nt < 4; nt++)
#pragma unroll
                    for (int r = 0; r < 4; r++) {
                        int keyg = nt * 16 + c;
                        int qg   = wave * 16 + quad * 4 + r;
                        if (keyg > qg) s[nt][r] = -1e30f;
                    }
            }

            // online softmax (exp2 domain)
            float mnew[4], alpha[4];
#pragma unroll
            for (int r = 0; r < 4; r++) {
                float v = fmaxf(fmaxf(s[0][r], s[1][r]), fmaxf(s[2][r], s[3][r]));
                v = fmaxf(v, __shfl_xor(v, 1));
                v = fmaxf(v, __shfl_xor(v, 2));
                v = fmaxf(v, __shfl_xor(v, 4));
                v = fmaxf(v, __shfl_xor(v, 8));
                mnew[r]  = fmaxf(ms[r], v);
                alpha[r] = exp2f(ms[r] - mnew[r]);
                ms[r]    = mnew[r];
            }
            float rs[4] = {0.f, 0.f, 0.f, 0.f};
#pragma unroll
            for (int nt = 0; nt < 4; nt++)
#pragma unroll
                for (int r = 0; r < 4; r++) {
                    float pv = exp2f(s[nt][r] - mnew[r]);
                    rs[r] += pv;
                    sP[wave][(quad * 4 + r) * 72 + nt * 16 + c] = f2bf(pv);
                }
#pragma unroll
            for (int r = 0; r < 4; r++) {
                float v = rs[r];
                v += __shfl_xor(v, 1);
                v += __shfl_xor(v, 2);
                v += __shfl_xor(v, 4);
                v += __shfl_xor(v, 8);
                ls[r] = ls[r] * alpha[r] + v;
            }
#pragma unroll
            for (int dt = 0; dt < 8; dt++)
#pragma unroll
                for (int r = 0; r < 4; r++) oa[dt][r] *= alpha[r];

            __asm__ volatile("s_waitcnt lgkmcnt(0)" ::: "memory");  // drain wave-private sP writes

            // O += P V
#pragma unroll
            for (int k2 = 0; k2 < 2; k2++) {
                bf16x8 pf = *(const bf16x8*)&sP[wave][c * 72 + k2 * 32 + quad * 8];
#pragma unroll
                for (int dt = 0; dt < 8; dt++) {
                    int ld = dt * 16 + c;
                    int gc = k2 * 4 + quad;
                    int pch = (gc ^ ld) & 7;
                    bf16x8 vf = *(const bf16x8*)&sVt[ld * 64 + pch * 8];
                    oa[dt] = __builtin_amdgcn_mfma_f32_16x16x32_bf16(pf, vf, oa[dt], 0, 0, 0);
                }
            }
        }

        // epilogue
#pragma unroll
        for (int r = 0; r < 4; r++) {
            float inv = 1.f / ls[r];
            int row = q0 + wave * 16 + quad * 4 + r;
#pragma unroll
            for (int dt = 0; dt < 8; dt++)
                O[(size_t)row * DIM + h * HD + dt * 16 + c] = f2bf(oa[dt][r] * inv);
        }
    }
}

extern "C" void kernel_launch(void* const* d_in, const int* in_sizes, int n_in,
                              void* d_out, int out_size, void* d_ws, size_t ws_size,
                              hipStream_t stream) {
    const float* x     = (const float*)d_in[0];
    const float* freqs = (const float*)d_in[2];
    const float* wq    = (const float*)d_in[4];
    const float* wk    = (const float*)d_in[5];
    const float* wv    = (const float*)d_in[6];
    const float* wo    = (const float*)d_in[7];
    float* out = (float*)d_out;

    ushort* xb    = (ushort*)d_ws;
    ushort* wqb   = xb    + (size_t)SEQ * DIM;
    ushort* wkb   = wqb   + (size_t)DIM * DIM;
    ushort* wvb   = wkb   + (size_t)DIM * DIM;
    ushort* wob   = wvb   + (size_t)DIM * DIM;
    ushort* qbuf  = wob   + (size_t)DIM * DIM;
    ushort* kbuf  = qbuf  + (size_t)SEQ * DIM;
    ushort* vtbuf = kbuf  + (size_t)SEQ * DIM;   // [DIM][SEQ] = V^T per head
    ushort* obuf  = vtbuf + (size_t)SEQ * DIM;

    const int n4tot = (SEQ * DIM + 4 * DIM * DIM) / 4;
    conv_all<<<n4tot / 256, 256, 0, stream>>>(x, wq, wk, wv, wo, xb, wqb, wkb, wvb, wob);

    // 16 m-tiles x (3*16) n-tiles of 128x256 = 768 blocks = 3 full rounds
    gemm_qkv<<<dim3(768), 512, 0, stream>>>(xb, wqb, wkb, wvb, qbuf, kbuf, vtbuf, freqs);

    flash_kernel<<<dim3(NH * SEQ / 128), 256, 0, stream>>>(qbuf, kbuf, vtbuf, obuf);

    // 16 m-tiles x 16 n-tiles of 128x256 = 256 blocks = 1 full round
    gemm_f32out<<<dim3(256), 512, 0, stream>>>(obuf, wob, out, SEQ, DIM, DIM);
}